// Round 1
// baseline (775.110 us; speedup 1.0000x reference)
//
#include <hip/hip_runtime.h>

#define N_NODES 4096
#define MJ      12288        // 4096 * 3 inner dimension (m-major, j stride-1 == W row layout)
#define KOUT    32
#define CH      512          // mj chunk staged in LDS
#define NCHUNK  24           // MJ / CH
#define ROWS    4            // W rows per wave
#define WAVES   4
#define TILE_ROWS 16         // ROWS * WAVES rows per workgroup

// ---------------- kernel 1: z[b][k][m*3+j] = sum_c conv_w[k][j*32+c] * x[b][m][c]
__global__ __launch_bounds__(256) void zprep_kernel(
    const float* __restrict__ x, const float* __restrict__ cw,
    float* __restrict__ z) {
  __shared__ float scw[3072];                     // conv_w [32][96]
  for (int i = threadIdx.x; i < 3072; i += 256) scw[i] = cw[i];
  __syncthreads();

  int bm = blockIdx.x * 256 + threadIdx.x;        // 0..8191 -> (b, m)
  const float* xp = x + (size_t)bm * 32;
  float xv[32];
  #pragma unroll
  for (int c4 = 0; c4 < 8; ++c4) {
    float4 v = ((const float4*)xp)[c4];
    xv[c4*4+0] = v.x; xv[c4*4+1] = v.y; xv[c4*4+2] = v.z; xv[c4*4+3] = v.w;
  }
  int b = bm >> 12, m = bm & 4095;
  float* zp = z + (size_t)b * (KOUT * MJ) + m * 3;
  #pragma unroll 1
  for (int k = 0; k < KOUT; ++k) {
    #pragma unroll
    for (int j = 0; j < 3; ++j) {
      float s = 0.f;
      #pragma unroll
      for (int c = 0; c < 32; ++c) s += scw[k*96 + j*32 + c] * xv[c];
      zp[(size_t)k * MJ + j] = s;
    }
  }
}

// ---------------- kernel 2: out[b][k][n] = sum_mj W[row][mj] * z[b][k][mj] + bias[k]
__global__ __launch_bounds__(256) void gemm_kernel(
    const float* __restrict__ W, const float* __restrict__ z,
    const float* __restrict__ bias, float* __restrict__ out) {
  __shared__ float zlds[KOUT][CH];                // 64 KB
  const int t = threadIdx.x;
  const int wave = t >> 6, lane = t & 63;
  const int row0 = blockIdx.x * TILE_ROWS + wave * ROWS;   // global row in [0, 8192)
  const int b = row0 >> 12;
  const float* zb = z + (size_t)b * (KOUT * MJ);
  const float* Wp = W + (size_t)row0 * MJ;        // (b*N+n)*MJ == row0*MJ

  float acc[ROWS][KOUT];
  #pragma unroll
  for (int r = 0; r < ROWS; ++r)
    #pragma unroll
    for (int k = 0; k < KOUT; ++k) acc[r][k] = 0.f;

  float4 wcur[2][ROWS], wnxt[2][ROWS];
  #pragma unroll
  for (int h = 0; h < 2; ++h)
    #pragma unroll
    for (int r = 0; r < ROWS; ++r)
      wcur[h][r] = *(const float4*)&Wp[(size_t)r * MJ + h * 256 + 4 * lane];

  for (int ch = 0; ch < NCHUNK; ++ch) {
    __syncthreads();                              // previous chunk fully consumed
    // stage z chunk [32][512] -> LDS, coalesced float4
    #pragma unroll
    for (int i = 0; i < 16; ++i) {
      int flat = t + i * 256;                     // float4 index into [32][128]
      int k = flat >> 7, c4 = flat & 127;
      *(float4*)&zlds[k][c4 * 4] =
          *(const float4*)&zb[(size_t)k * MJ + ch * CH + c4 * 4];
    }
    __syncthreads();

    if (ch + 1 < NCHUNK) {                        // prefetch next chunk's W rows
      #pragma unroll
      for (int h = 0; h < 2; ++h)
        #pragma unroll
        for (int r = 0; r < ROWS; ++r)
          wnxt[h][r] = *(const float4*)&Wp[(size_t)r * MJ + (ch + 1) * CH + h * 256 + 4 * lane];
    }

    #pragma unroll
    for (int h = 0; h < 2; ++h) {
      #pragma unroll
      for (int k = 0; k < KOUT; ++k) {
        float4 zv = *(const float4*)&zlds[k][h * 256 + 4 * lane];
        #pragma unroll
        for (int r = 0; r < ROWS; ++r) {
          float4 wv = wcur[h][r];
          acc[r][k] += wv.x * zv.x;
          acc[r][k] += wv.y * zv.y;
          acc[r][k] += wv.z * zv.z;
          acc[r][k] += wv.w * zv.w;
        }
      }
    }
    #pragma unroll
    for (int h = 0; h < 2; ++h)
      #pragma unroll
      for (int r = 0; r < ROWS; ++r) wcur[h][r] = wnxt[h][r];
  }

  // -------- epilogue: reduce partial sums across the 64 lanes
  #pragma unroll
  for (int r = 0; r < ROWS; ++r)
    #pragma unroll
    for (int k = 0; k < KOUT; ++k) {
      acc[r][k] += __shfl_xor(acc[r][k], 1, 64);
      acc[r][k] += __shfl_xor(acc[r][k], 2, 64);
    }
  __syncthreads();                                // done reading zlds; safe to alias
  float* part = &zlds[0][0];                      // [64 groups][129 floats], 33 KB
  if ((lane & 3) == 0) {
    int l4 = lane >> 2;                           // 0..15
    float* p = part + (size_t)(wave * 16 + l4) * 129;
    #pragma unroll
    for (int r = 0; r < ROWS; ++r)
      #pragma unroll
      for (int k = 0; k < KOUT; ++k) p[r * 32 + k] = acc[r][k];
  }
  __syncthreads();

  for (int o = t; o < 512; o += 256) {            // 2 outputs per thread
    int k = o >> 4, rg = o & 15;
    int w = rg >> 2, r = rg & 3;
    float s = 0.f;
    #pragma unroll
    for (int l4 = 0; l4 < 16; ++l4)
      s += part[(size_t)(w * 16 + l4) * 129 + r * 32 + k];
    s += bias[k];
    int row = blockIdx.x * TILE_ROWS + rg;
    int bb = row >> 12, n = row & 4095;
    out[((size_t)bb * KOUT + k) * N_NODES + n] = s;
  }
}

extern "C" void kernel_launch(void* const* d_in, const int* in_sizes, int n_in,
                              void* d_out, int out_size, void* d_ws, size_t ws_size,
                              hipStream_t stream) {
  const float* W  = (const float*)d_in[0];   // (2,4096,4096,3)
  const float* x  = (const float*)d_in[1];   // (2,4096,32)
  const float* cw = (const float*)d_in[2];   // (32,96)
  const float* cb = (const float*)d_in[3];   // (32,)
  float* out = (float*)d_out;                // (2,32,4096,1)
  float* z   = (float*)d_ws;                 // 2*32*12288 floats = 3 MB scratch

  zprep_kernel<<<32, 256, 0, stream>>>(x, cw, z);
  gemm_kernel<<<512, 256, 0, stream>>>(W, z, cb, out);
}

// Round 2
// 565.081 us; speedup vs baseline: 1.3717x; 1.3717x over previous
//
#include <hip/hip_runtime.h>

#define MJ      12288        // 4096*3, W row layout (m-major, j stride-1)
#define KOUT    32
#define CH      256          // mj chunk staged in LDS
#define NCHUNK  48           // MJ / CH
#define ROWS    4            // W rows per wave
#define TILE_ROWS 16         // rows per workgroup (4 waves)
#define NB      4096

typedef __attribute__((address_space(1))) const void gas_t;
typedef __attribute__((address_space(3))) void las_t;

// ---------------- kernel 1: z[b][k][m*3+j] = sum_c conv_w[k][j*32+c] * x[b][m][c]
// grid 1024 x 256: block covers 8 (b,m) pairs x 32 k
__global__ __launch_bounds__(256) void zprep_kernel(
    const float* __restrict__ x, const float* __restrict__ cw,
    float* __restrict__ z) {
  __shared__ float scw[32 * 97];                  // conv_w rows padded 96->97 (bank spread)
  __shared__ float sx[8][33];                     // x tile padded 32->33
  const int t = threadIdx.x;
  for (int i = t; i < 3072; i += 256) scw[(i / 96) * 97 + (i % 96)] = cw[i];
  const int bm0 = blockIdx.x * 8;
  if (t < 64) {
    int i = t >> 3, c4 = t & 7;
    float4 v = *(const float4*)&x[((size_t)(bm0 + i)) * 32 + c4 * 4];
    sx[i][c4 * 4 + 0] = v.x; sx[i][c4 * 4 + 1] = v.y;
    sx[i][c4 * 4 + 2] = v.z; sx[i][c4 * 4 + 3] = v.w;
  }
  __syncthreads();
  const int i = t & 7, k = t >> 3;                // lane&7 -> distinct sx banks; k*97 -> distinct scw banks
  const int bm = bm0 + i, b = bm >> 12, m = bm & 4095;
  float o0 = 0.f, o1 = 0.f, o2 = 0.f;
  #pragma unroll
  for (int c = 0; c < 32; ++c) {
    float xv = sx[i][c];
    o0 += scw[k * 97 + c] * xv;
    o1 += scw[k * 97 + 32 + c] * xv;
    o2 += scw[k * 97 + 64 + c] * xv;
  }
  float* zp = z + (size_t)b * (KOUT * (size_t)MJ) + (size_t)k * MJ + (size_t)m * 3;
  zp[0] = o0; zp[1] = o1; zp[2] = o2;
}

// ---------------- kernel 2: out[b][k][n] = sum_mj W[row][mj] * z[b][k][mj] + bias[k]
// 512 blocks x 256 threads; 2 blocks/CU; double-buffered z via global_load_lds
__global__ __launch_bounds__(256, 2) void gemm_kernel(
    const float* __restrict__ W, const float* __restrict__ z,
    const float* __restrict__ bias, float* __restrict__ out) {
  __shared__ float zl[2][KOUT][CH];               // 2 x 32 KB double buffer
  const int t = threadIdx.x, wave = t >> 6, lane = t & 63;
  const int row0 = blockIdx.x * TILE_ROWS + wave * ROWS;
  const int b = row0 >> 12;
  const float* zb = z + (size_t)b * (KOUT * (size_t)MJ);
  const float* Wp = W + (size_t)row0 * MJ + lane * 4;

  float acc[ROWS][KOUT];
  #pragma unroll
  for (int r = 0; r < ROWS; ++r)
    #pragma unroll
    for (int k = 0; k < KOUT; ++k) acc[r][k] = 0.f;

  float4 wcur[ROWS], wnxt[ROWS];

  // prologue: stage chunk 0, load W(0)
  #pragma unroll
  for (int ii = 0; ii < 8; ++ii) {
    int k = wave * 8 + ii;                        // each wave stages 8 z-rows; hw puts lane l at base+16*l
    const float* gp = zb + (size_t)k * MJ + lane * 4;
    __builtin_amdgcn_global_load_lds((gas_t*)gp, (las_t*)&zl[0][k][0], 16, 0, 0);
  }
  #pragma unroll
  for (int r = 0; r < ROWS; ++r) wcur[r] = *(const float4*)&Wp[(size_t)r * MJ];
  __syncthreads();                                // implicit vmcnt(0) drain covers global_load_lds

  for (int ch = 0; ch < NCHUNK; ++ch) {
    const int p = ch & 1;
    if (ch + 1 < NCHUNK) {                        // issue next chunk BEFORE computing current
      #pragma unroll
      for (int ii = 0; ii < 8; ++ii) {
        int k = wave * 8 + ii;
        const float* gp = zb + (size_t)k * MJ + (ch + 1) * CH + lane * 4;
        __builtin_amdgcn_global_load_lds((gas_t*)gp, (las_t*)&zl[p ^ 1][k][0], 16, 0, 0);
      }
      #pragma unroll
      for (int r = 0; r < ROWS; ++r)
        wnxt[r] = *(const float4*)&Wp[(size_t)r * MJ + (ch + 1) * CH];
    }
    // compute chunk ch: 32 ds_read_b128 + 512 v_fmac per lane
    #pragma unroll
    for (int k = 0; k < KOUT; ++k) {
      float4 zv = *(const float4*)&zl[p][k][lane * 4];
      #pragma unroll
      for (int r = 0; r < ROWS; ++r) {
        acc[r][k] += wcur[r].x * zv.x;
        acc[r][k] += wcur[r].y * zv.y;
        acc[r][k] += wcur[r].z * zv.z;
        acc[r][k] += wcur[r].w * zv.w;
      }
    }
    if (ch + 1 < NCHUNK) {
      #pragma unroll
      for (int r = 0; r < ROWS; ++r) wcur[r] = wnxt[r];  // compiler inserts vmcnt wait here
      __syncthreads();                            // stages of buf p^1 complete; reads of buf p done
    }
  }

  // -------- epilogue: reduce over the 64-lane mj split
  #pragma unroll
  for (int r = 0; r < ROWS; ++r)
    #pragma unroll
    for (int k = 0; k < KOUT; ++k) {
      acc[r][k] += __shfl_xor(acc[r][k], 1, 64);
      acc[r][k] += __shfl_xor(acc[r][k], 2, 64);
    }
  __syncthreads();                                // all waves done reading zl; safe to alias
  float* part = &zl[0][0][0];                     // [64 groups][129 floats] = 33 KB
  if ((lane & 3) == 0) {
    float* p2 = part + (size_t)(wave * 16 + (lane >> 2)) * 129;
    #pragma unroll
    for (int r = 0; r < ROWS; ++r)
      #pragma unroll
      for (int k = 0; k < KOUT; ++k) p2[r * 32 + k] = acc[r][k];
  }
  __syncthreads();

  #pragma unroll
  for (int o = t; o < 512; o += 256) {            // 2 outputs per thread
    int k = o >> 4, rg = o & 15;
    int w = rg >> 2, r = rg & 3;
    float s = bias[k];
    #pragma unroll
    for (int l4 = 0; l4 < 16; ++l4)
      s += part[(size_t)(w * 16 + l4) * 129 + r * 32 + k];
    int row = blockIdx.x * TILE_ROWS + rg;
    int bb = row >> 12, n = row & 4095;
    out[((size_t)bb * KOUT + k) * NB + n] = s;
  }
}

extern "C" void kernel_launch(void* const* d_in, const int* in_sizes, int n_in,
                              void* d_out, int out_size, void* d_ws, size_t ws_size,
                              hipStream_t stream) {
  const float* W  = (const float*)d_in[0];   // (2,4096,4096,3)
  const float* x  = (const float*)d_in[1];   // (2,4096,32)
  const float* cw = (const float*)d_in[2];   // (32,96)
  const float* cb = (const float*)d_in[3];   // (32,)
  float* out = (float*)d_out;                // (2,32,4096,1)
  float* z   = (float*)d_ws;                 // 2*32*12288 floats = 3 MB scratch

  zprep_kernel<<<1024, 256, 0, stream>>>(x, cw, z);
  gemm_kernel<<<512, 256, 0, stream>>>(W, z, cb, out);
}